// Round 2
// baseline (400.133 us; speedup 1.0000x reference)
//
#include <hip/hip_runtime.h>
#include <hip/hip_bf16.h>

// QLSTMClassifier: Embedding -> QLSTM (closed-form quantum layer) -> Linear -> log_softmax
// S=256 (batch==seq), E=1024, H=10, V=50257, T=50.
//
// ROUND 1 RESTRUCTURE: the (t,b)-gather GEMM was bandwidth-PATTERN-bound
// (random 4KB rows). z depends only on the token id, so:
//  k_wt   : Wg x-part -> Bfg (bf16 MFMA B-fragments), unchanged.
//  k_gemm : DENSE STREAMING zu[v][40] = emb[v] @ W for ALL 50257 vocab rows.
//           Sequential 206 MB read at full HBM BW; no gather, no zs.
//  k_rnn  : producer wave gathers zu[idx[t*256+b]] rows (160 B, L3-hot) into
//           the LDS ring; consumer chain unchanged (bit-identical numerics).
//  k_head : unchanged.
//
// ws (floats): Bfg[24576 eq] | zu[50257*40] | outs[65536*10]  (~10.8 MB)

#define E_DIM 1024
#define H_DIM 10
#define NC 40
#define V_DIM 50257
#define EHS 10340      // (E+H)*H per-gate Wg stride

typedef __attribute__((ext_vector_type(8))) short bf16x8;
typedef __attribute__((ext_vector_type(4))) float f32x4;

__device__ __forceinline__ unsigned short f2bf(float f) {
    unsigned u = __float_as_uint(f);
    unsigned r = u + 0x7FFFu + ((u >> 16) & 1u);   // RNE
    return (unsigned short)(r >> 16);
}

// ---------------- kernel 0: Wg -> bf16 B-fragments ----------------
// Bfg[((c*3+nt)*64+lane)*8 + j] = bf16(W[k][nc]), k=c*32+(lane>>4)*8+j, nc=nt*16+(lane&15)
__global__ __launch_bounds__(256) void k_wt(const float* __restrict__ Wg,
                                            unsigned short* __restrict__ Bfg) {
    int i = blockIdx.x * 256 + threadIdx.x;     // < 32*3*64 = 6144
    if (i >= 6144) return;
    int lane = i & 63, nt = (i >> 6) % 3, c = i / 192;
    int kg = lane >> 4, n = lane & 15;
    int nc = nt * 16 + n;
    unsigned short v[8];
#pragma unroll
    for (int j = 0; j < 8; ++j) {
        int k = c * 32 + kg * 8 + j;
        float w = 0.0f;
        if (nc < NC) {
            int g = nc / H_DIM, h = nc % H_DIM;
            w = Wg[g * EHS + k * H_DIM + h];
        }
        v[j] = f2bf(w);
    }
    bf16x8* dst = (bf16x8*)(Bfg + (size_t)i * 8);
    bf16x8 pk;
#pragma unroll
    for (int j = 0; j < 8; ++j) pk[j] = (short)v[j];
    *dst = pk;
}

// ---------------- kernel 1: DENSE vocab GEMM via MFMA ----------------
// zu[v][40] = emb[v] @ W for every vocab row. grid 786 x block 256 (4 waves),
// wave handles 16 consecutive rows -> purely sequential streaming of emb.
__global__ __launch_bounds__(256, 4) void k_gemm(const float* __restrict__ emb,
                                                 const unsigned short* __restrict__ Bfg,
                                                 float* __restrict__ zu) {
    const int tid = threadIdx.x;
    const int wave = tid >> 6, lane = tid & 63;
    const int R0 = (blockIdx.x * 4 + wave) * 16;
    const int m = lane & 15, q = lane >> 4;

    int row = R0 + m;
    if (row > V_DIM - 1) row = V_DIM - 1;       // clamp loads; stores masked below
    const float* arow = emb + (size_t)row * E_DIM + q * 8;

    f32x4 acc0 = {0.f, 0.f, 0.f, 0.f}, acc1 = acc0, acc2 = acc0;

#pragma unroll 2
    for (int c = 0; c < 32; ++c) {
        float4 a0 = *(const float4*)(arow + c * 32);
        float4 a1 = *(const float4*)(arow + c * 32 + 4);
        bf16x8 b0 = *(const bf16x8*)(Bfg + ((size_t)(c * 3 + 0) * 64 + lane) * 8);
        bf16x8 b1 = *(const bf16x8*)(Bfg + ((size_t)(c * 3 + 1) * 64 + lane) * 8);
        bf16x8 b2 = *(const bf16x8*)(Bfg + ((size_t)(c * 3 + 2) * 64 + lane) * 8);
        bf16x8 af;
        af[0] = (short)f2bf(a0.x); af[1] = (short)f2bf(a0.y);
        af[2] = (short)f2bf(a0.z); af[3] = (short)f2bf(a0.w);
        af[4] = (short)f2bf(a1.x); af[5] = (short)f2bf(a1.y);
        af[6] = (short)f2bf(a1.z); af[7] = (short)f2bf(a1.w);
        acc0 = __builtin_amdgcn_mfma_f32_16x16x32_bf16(af, b0, acc0, 0, 0, 0);
        acc1 = __builtin_amdgcn_mfma_f32_16x16x32_bf16(af, b1, acc1, 0, 0, 0);
        acc2 = __builtin_amdgcn_mfma_f32_16x16x32_bf16(af, b2, acc2, 0, 0, 0);
    }

    // C/D layout: col = lane&15, row = (lane>>4)*4 + reg
    const int r0 = R0 + q * 4;
#pragma unroll
    for (int i = 0; i < 4; ++i) {
        int r = r0 + i;
        if (r < V_DIM) {
            size_t o = (size_t)r * NC;
            zu[o + m] = acc0[i];
            zu[o + 16 + m] = acc1[i];
            if (m < 8) zu[o + 32 + m] = acc2[i];
        }
    }
}

// ---------------- kernel 2: QLSTM recurrence, producer/consumer ----------------
template <int CTRL>
__device__ __forceinline__ float dpp1(float x) {
    // shifted value; out-of-range lanes keep identity 1.0 (old value, bound_ctrl=false)
    return __int_as_float(__builtin_amdgcn_update_dpp(
        __float_as_int(1.0f), __float_as_int(x), CTRL, 0xF, 0xF, false));
}
#define ROW_SHR(n) (0x110 + (n))
#define ROW_SHL(n) (0x100 + (n))

__device__ __forceinline__ float rdlane(float v, int l) {
    return __int_as_float(__builtin_amdgcn_readlane(__float_as_int(v), l));
}

__global__ __launch_bounds__(128) void k_rnn(const int* __restrict__ idx,
                                             const float* __restrict__ zu,
                                             const float* __restrict__ Wg,
                                             const float* __restrict__ bg,
                                             const float* __restrict__ theta,
                                             float* __restrict__ outs) {
    __shared__ float zbuf[2][640];   // 16 steps x 40 per buffer
    __shared__ int toks[256];        // token ids for this batch lane b, t=0..255
    const int tid = threadIdx.x;
    const int b = blockIdx.x;

    if (tid >= 64) {
        // ---- producer wave: gather zu rows for 16 steps at a time ----
        const int p = tid - 64;
#pragma unroll
        for (int k = 0; k < 4; ++k) toks[p + k * 64] = idx[(p + k * 64) * 256 + b];
        const int j = p >> 2;        // row-in-block 0..15
        const int s4 = p & 3;        // quarter of the 40-float row
        {
            int tv = toks[j];        // blk 0
            const float* src = zu + (size_t)tv * NC + s4 * 10;
            float* dst = &zbuf[0][j * 40 + s4 * 10];
#pragma unroll
            for (int e = 0; e < 5; ++e)
                *(float2*)(dst + 2 * e) = *(const float2*)(src + 2 * e);
        }
        __syncthreads();
        for (int blk = 0; blk < 16; ++blk) {
            if (blk + 1 < 16) {
                int tv = toks[(blk + 1) * 16 + j];
                const float* src = zu + (size_t)tv * NC + s4 * 10;
                float v[10];
#pragma unroll
                for (int e = 0; e < 5; ++e) {
                    float2 t2 = *(const float2*)(src + 2 * e);
                    v[2 * e] = t2.x; v[2 * e + 1] = t2.y;
                }
                float* dst = &zbuf[(blk + 1) & 1][j * 40 + s4 * 10];
#pragma unroll
                for (int e = 0; e < 5; ++e) {
                    float2 t2 = {v[2 * e], v[2 * e + 1]};
                    *(float2*)(dst + 2 * e) = t2;
                }
            }
            __syncthreads();
        }
    } else {
        // ---- consumer wave: the serial chain (unchanged) ----
        const int lane = tid;
        const int r = lane >> 4;            // gate 0..3 (f,i,g,o)
        const int h = lane & 15;            // wire; valid < 10
        const int hc = (h < 10) ? h : 9;
        const int cidx = r * 10 + hc;

        float Wh[10];
#pragma unroll
        for (int j = 0; j < 10; ++j) Wh[j] = Wg[r * EHS + (E_DIM + j) * H_DIM + hc];
        const float bias = bg[cidx] + theta[cidx];

        const float kk = (r == 2) ? 2.0f : -1.0f;   // tanh : sigmoid
        const float aa = (r == 2) ? 1.0f : 0.0f;
        const float bb = (r == 2) ? -2.0f : 1.0f;

        float cx = 0.0f, hx = 0.0f;
        __syncthreads();

        for (int blk = 0; blk < 16; ++blk) {
            const float* zb = zbuf[blk & 1];
            float zv = zb[cidx];
#pragma unroll 4
            for (int s = 0; s < 16; ++s) {
                float znext = zb[((s < 15) ? (s + 1) * 40 : s * 40) + cidx];

                // hx[0..9] live on lanes 0..9 -> SGPR broadcasts
                float hv0 = rdlane(hx, 0), hv1 = rdlane(hx, 1), hv2 = rdlane(hx, 2),
                      hv3 = rdlane(hx, 3), hv4 = rdlane(hx, 4), hv5 = rdlane(hx, 5),
                      hv6 = rdlane(hx, 6), hv7 = rdlane(hx, 7), hv8 = rdlane(hx, 8),
                      hv9 = rdlane(hx, 9);
                float d0 = fmaf(hv0, Wh[0], fmaf(hv2, Wh[2],
                           fmaf(hv4, Wh[4], fmaf(hv6, Wh[6], hv8 * Wh[8]))));
                float d1 = fmaf(hv1, Wh[1], fmaf(hv3, Wh[3],
                           fmaf(hv5, Wh[5], fmaf(hv7, Wh[7], hv9 * Wh[9]))));
                float z = (zv + bias) + (d0 + d1);

                float cc = __builtin_amdgcn_cosf(z * 0.15915494309189535f);

                // inclusive prefix product P[h] = prod_{j<=h} c_j
                float pp = cc;
                pp *= dpp1<ROW_SHR(1)>(pp);
                pp *= dpp1<ROW_SHR(2)>(pp);
                pp *= dpp1<ROW_SHR(4)>(pp);
                pp *= dpp1<ROW_SHR(8)>(pp);
                // suffix product (pad lanes h>=10 with identity)
                float ss = (h < 10) ? cc : 1.0f;
                ss *= dpp1<ROW_SHL(1)>(ss);
                ss *= dpp1<ROW_SHL(2)>(ss);
                ss *= dpp1<ROW_SHL(4)>(ss);
                ss *= dpp1<ROW_SHL(8)>(ss);
                float tl = dpp1<ROW_SHL(1)>(ss);     // lane 0 -> prod_{j>=1}
                float qv = (h == 0) ? tl : pp;

                float e = __expf(kk * qv);
                float act = fmaf(bb, __builtin_amdgcn_rcpf(1.0f + e), aa);

                // gather f,i,g,o for wire h (lanes h, 16+h, 32+h, 48+h)
                float fv = __shfl(act, h);
                float iv = __shfl(act, 16 + h);
                float gv = __shfl(act, 32 + h);
                float ov = __shfl(act, 48 + h);

                cx = fmaf(fv, cx, iv * gv);
                float e2 = __expf(2.0f * cx);
                float th = fmaf(-2.0f, __builtin_amdgcn_rcpf(1.0f + e2), 1.0f);
                hx = ov * th;

                int t = blk * 16 + s;
                if (lane < 10) outs[((size_t)t * 256 + b) * H_DIM + lane] = hx;
                zv = znext;
            }
            __syncthreads();
        }
    }
}

// ---------------- kernel 3: hidden2tag + log_softmax, thread per row ----------------
__global__ __launch_bounds__(256) void k_head(const float* __restrict__ outs,
                                              const float* __restrict__ Wo,
                                              const float* __restrict__ bo,
                                              float* __restrict__ out) {
    const size_t row = blockIdx.x * 256 + threadIdx.x;   // < 65536
    float hx[10];
#pragma unroll
    for (int i = 0; i < 5; ++i) {
        float2 v = *(const float2*)&outs[row * H_DIM + 2 * i];
        hx[2 * i] = v.x; hx[2 * i + 1] = v.y;
    }
    float lg[50];
#pragma unroll
    for (int cI = 0; cI < 50; ++cI) {
        float l = bo[cI];
#pragma unroll
        for (int j = 0; j < 10; ++j) l = fmaf(hx[j], Wo[j * 50 + cI], l);
        lg[cI] = l;
    }
    float m = lg[0];
#pragma unroll
    for (int cI = 1; cI < 50; ++cI) m = fmaxf(m, lg[cI]);
    float sum = 0.0f;
#pragma unroll
    for (int cI = 0; cI < 50; ++cI) sum += __expf(lg[cI] - m);
    float lse = m + __logf(sum);
#pragma unroll
    for (int i = 0; i < 25; ++i) {
        float2 v = {lg[2 * i] - lse, lg[2 * i + 1] - lse};
        *(float2*)&out[row * 50 + 2 * i] = v;
    }
}

extern "C" void kernel_launch(void* const* d_in, const int* in_sizes, int n_in,
                              void* d_out, int out_size, void* d_ws, size_t ws_size,
                              hipStream_t stream) {
    const int*   sentence = (const int*)d_in[0];     // (256,256)
    const float* emb      = (const float*)d_in[1];   // (50257,1024)
    const float* Wg       = (const float*)d_in[2];   // (4,1034,10)
    const float* bg       = (const float*)d_in[3];   // (4,10)
    const float* theta    = (const float*)d_in[4];   // (4,10)
    const float* Wo       = (const float*)d_in[5];   // (10,50)
    const float* bo       = (const float*)d_in[6];   // (50,)
    float* out = (float*)d_out;

    float* ws = (float*)d_ws;
    unsigned short* Bfg = (unsigned short*)ws;            // 49152 shorts = 24576 floats
    float* zu   = ws + 24576;                             // 50257*40 floats (~8.0 MB)
    float* outs = zu + (size_t)V_DIM * NC;                // 65536*10

    k_wt<<<24, 256, 0, stream>>>(Wg, Bfg);
    k_gemm<<<786, 256, 0, stream>>>(emb, Bfg, zu);
    k_rnn<<<256, 128, 0, stream>>>(sentence, zu, Wg, bg, theta, outs);
    k_head<<<256, 256, 0, stream>>>(outs, Wo, bo, out);
}

// Round 4
// 387.078 us; speedup vs baseline: 1.0337x; 1.0337x over previous
//
#include <hip/hip_runtime.h>
#include <hip/hip_bf16.h>

// QLSTMClassifier: Embedding -> QLSTM (closed-form quantum layer) -> Linear -> log_softmax
// S=256 (batch==seq), E=1024, H=10, V=50257, T=50.
//
//  k_wt   : Wg x-part -> Bfg (bf16 MFMA B-fragments). unchanged.
//  k_gemm : DENSE STREAMING zu[v][40] = emb[v] @ W for all vocab rows
//           (206 MB sequential read ~ BW floor). Nontemporal emb loads keep
//           Bfg/zu cache-resident for the rnn gather.
//  k_rnn  : all 128 threads gather the whole 256x40 z-panel (40 KB) into LDS
//           with ~80 independent loads per thread, ONE syncthreads, wave 1
//           exits, consumer runs the 256-step serial chain barrier-free.
//  k_head : unchanged.
//
// ws (floats): Bfg[24576 eq] | zu[50257*40] | outs[65536*10]  (~10.8 MB)

#define E_DIM 1024
#define H_DIM 10
#define NC 40
#define V_DIM 50257
#define EHS 10340      // (E+H)*H per-gate Wg stride

typedef __attribute__((ext_vector_type(8))) short bf16x8;
typedef __attribute__((ext_vector_type(4))) float f32x4;

__device__ __forceinline__ unsigned short f2bf(float f) {
    unsigned u = __float_as_uint(f);
    unsigned r = u + 0x7FFFu + ((u >> 16) & 1u);   // RNE
    return (unsigned short)(r >> 16);
}

// ---------------- kernel 0: Wg -> bf16 B-fragments ----------------
// Bfg[((c*3+nt)*64+lane)*8 + j] = bf16(W[k][nc]), k=c*32+(lane>>4)*8+j, nc=nt*16+(lane&15)
__global__ __launch_bounds__(256) void k_wt(const float* __restrict__ Wg,
                                            unsigned short* __restrict__ Bfg) {
    int i = blockIdx.x * 256 + threadIdx.x;     // < 32*3*64 = 6144
    if (i >= 6144) return;
    int lane = i & 63, nt = (i >> 6) % 3, c = i / 192;
    int kg = lane >> 4, n = lane & 15;
    int nc = nt * 16 + n;
    unsigned short v[8];
#pragma unroll
    for (int j = 0; j < 8; ++j) {
        int k = c * 32 + kg * 8 + j;
        float w = 0.0f;
        if (nc < NC) {
            int g = nc / H_DIM, h = nc % H_DIM;
            w = Wg[g * EHS + k * H_DIM + h];
        }
        v[j] = f2bf(w);
    }
    bf16x8* dst = (bf16x8*)(Bfg + (size_t)i * 8);
    bf16x8 pk;
#pragma unroll
    for (int j = 0; j < 8; ++j) pk[j] = (short)v[j];
    *dst = pk;
}

// ---------------- kernel 1: DENSE vocab GEMM via MFMA ----------------
// zu[v][40] = emb[v] @ W for every vocab row. grid 786 x block 256 (4 waves),
// wave handles 16 consecutive rows -> purely sequential streaming of emb.
__global__ __launch_bounds__(256, 4) void k_gemm(const float* __restrict__ emb,
                                                 const unsigned short* __restrict__ Bfg,
                                                 float* __restrict__ zu) {
    const int tid = threadIdx.x;
    const int wave = tid >> 6, lane = tid & 63;
    const int R0 = (blockIdx.x * 4 + wave) * 16;
    const int m = lane & 15, q = lane >> 4;

    int row = R0 + m;
    if (row > V_DIM - 1) row = V_DIM - 1;       // clamp loads; stores masked below
    const float* arow = emb + (size_t)row * E_DIM + q * 8;

    f32x4 acc0 = {0.f, 0.f, 0.f, 0.f}, acc1 = acc0, acc2 = acc0;

#pragma unroll 2
    for (int c = 0; c < 32; ++c) {
        f32x4 a0 = __builtin_nontemporal_load((const f32x4*)(arow + c * 32));
        f32x4 a1 = __builtin_nontemporal_load((const f32x4*)(arow + c * 32 + 4));
        bf16x8 b0 = *(const bf16x8*)(Bfg + ((size_t)(c * 3 + 0) * 64 + lane) * 8);
        bf16x8 b1 = *(const bf16x8*)(Bfg + ((size_t)(c * 3 + 1) * 64 + lane) * 8);
        bf16x8 b2 = *(const bf16x8*)(Bfg + ((size_t)(c * 3 + 2) * 64 + lane) * 8);
        bf16x8 af;
        af[0] = (short)f2bf(a0[0]); af[1] = (short)f2bf(a0[1]);
        af[2] = (short)f2bf(a0[2]); af[3] = (short)f2bf(a0[3]);
        af[4] = (short)f2bf(a1[0]); af[5] = (short)f2bf(a1[1]);
        af[6] = (short)f2bf(a1[2]); af[7] = (short)f2bf(a1[3]);
        acc0 = __builtin_amdgcn_mfma_f32_16x16x32_bf16(af, b0, acc0, 0, 0, 0);
        acc1 = __builtin_amdgcn_mfma_f32_16x16x32_bf16(af, b1, acc1, 0, 0, 0);
        acc2 = __builtin_amdgcn_mfma_f32_16x16x32_bf16(af, b2, acc2, 0, 0, 0);
    }

    // C/D layout: col = lane&15, row = (lane>>4)*4 + reg
    const int r0 = R0 + q * 4;
#pragma unroll
    for (int i = 0; i < 4; ++i) {
        int r = r0 + i;
        if (r < V_DIM) {
            size_t o = (size_t)r * NC;
            zu[o + m] = acc0[i];
            zu[o + 16 + m] = acc1[i];
            if (m < 8) zu[o + 32 + m] = acc2[i];
        }
    }
}

// ---------------- kernel 2: QLSTM recurrence ----------------
template <int CTRL>
__device__ __forceinline__ float dpp1(float x) {
    // shifted value; out-of-range lanes keep identity 1.0 (old value, bound_ctrl=false)
    return __int_as_float(__builtin_amdgcn_update_dpp(
        __float_as_int(1.0f), __float_as_int(x), CTRL, 0xF, 0xF, false));
}
#define ROW_SHR(n) (0x110 + (n))
#define ROW_SHL(n) (0x100 + (n))

__device__ __forceinline__ float rdlane(float v, int l) {
    return __int_as_float(__builtin_amdgcn_readlane(__float_as_int(v), l));
}

// block 128: all threads gather the full z-panel into LDS (one sync),
// then wave 0 runs the 256-step serial chain barrier-free; wave 1 exits.
__global__ __launch_bounds__(128) void k_rnn(const int* __restrict__ idx,
                                             const float* __restrict__ zu,
                                             const float* __restrict__ Wg,
                                             const float* __restrict__ bg,
                                             const float* __restrict__ theta,
                                             float* __restrict__ outs) {
    __shared__ float zall[256 * NC];   // 40 KB: z for every step of this batch lane
    const int tid = threadIdx.x;
    const int b = blockIdx.x;

    // ---- cooperative gather: thread covers rows (pass*32 + tid>>2), quarter tid&3 ----
    {
        const int j = tid >> 2;        // 0..31
        const int qq = tid & 3;        // quarter of the 40-float row
        int tok[8];
#pragma unroll
        for (int pass = 0; pass < 8; ++pass)
            tok[pass] = idx[(size_t)(pass * 32 + j) * 256 + b];
#pragma unroll
        for (int pass = 0; pass < 8; ++pass) {
            const float* src = zu + (size_t)tok[pass] * NC + qq * 10;
            float* dst = &zall[(pass * 32 + j) * NC + qq * 10];
#pragma unroll
            for (int e = 0; e < 5; ++e)
                *(float2*)(dst + 2 * e) = *(const float2*)(src + 2 * e);
        }
    }
    __syncthreads();
    if (tid >= 64) return;             // producer wave done

    // ---- consumer wave: the serial chain (math unchanged) ----
    const int lane = tid;
    const int r = lane >> 4;            // gate 0..3 (f,i,g,o)
    const int h = lane & 15;            // wire; valid < 10
    const int hc = (h < 10) ? h : 9;
    const int cidx = r * 10 + hc;

    float Wh[10];
#pragma unroll
    for (int j = 0; j < 10; ++j) Wh[j] = Wg[r * EHS + (E_DIM + j) * H_DIM + hc];
    const float bias = bg[cidx] + theta[cidx];

    const float kk = (r == 2) ? 2.0f : -1.0f;   // tanh : sigmoid
    const float aa = (r == 2) ? 1.0f : 0.0f;
    const float bb = (r == 2) ? -2.0f : 1.0f;

    float cx = 0.0f, hx = 0.0f;
    float zv = zall[cidx];              // t = 0
#pragma unroll 8
    for (int t = 0; t < 256; ++t) {
        // prefetch next step's z early (hides ds_read latency under the chain)
        float znext = zall[((t < 255) ? (t + 1) : t) * NC + cidx];

        // hx[0..9] live on lanes 0..9 -> SGPR broadcasts
        float hv0 = rdlane(hx, 0), hv1 = rdlane(hx, 1), hv2 = rdlane(hx, 2),
              hv3 = rdlane(hx, 3), hv4 = rdlane(hx, 4), hv5 = rdlane(hx, 5),
              hv6 = rdlane(hx, 6), hv7 = rdlane(hx, 7), hv8 = rdlane(hx, 8),
              hv9 = rdlane(hx, 9);
        float d0 = fmaf(hv0, Wh[0], fmaf(hv2, Wh[2],
                   fmaf(hv4, Wh[4], fmaf(hv6, Wh[6], hv8 * Wh[8]))));
        float d1 = fmaf(hv1, Wh[1], fmaf(hv3, Wh[3],
                   fmaf(hv5, Wh[5], fmaf(hv7, Wh[7], hv9 * Wh[9]))));
        float z = (zv + bias) + (d0 + d1);

        float cc = __builtin_amdgcn_cosf(z * 0.15915494309189535f);

        // inclusive prefix product P[h] = prod_{j<=h} c_j
        float pp = cc;
        pp *= dpp1<ROW_SHR(1)>(pp);
        pp *= dpp1<ROW_SHR(2)>(pp);
        pp *= dpp1<ROW_SHR(4)>(pp);
        pp *= dpp1<ROW_SHR(8)>(pp);
        // suffix product (pad lanes h>=10 with identity)
        float ss = (h < 10) ? cc : 1.0f;
        ss *= dpp1<ROW_SHL(1)>(ss);
        ss *= dpp1<ROW_SHL(2)>(ss);
        ss *= dpp1<ROW_SHL(4)>(ss);
        ss *= dpp1<ROW_SHL(8)>(ss);
        float tl = dpp1<ROW_SHL(1)>(ss);     // lane 0 -> prod_{j>=1}
        float qv = (h == 0) ? tl : pp;

        float e = __expf(kk * qv);
        float act = fmaf(bb, __builtin_amdgcn_rcpf(1.0f + e), aa);

        // gather f,i,g,o for wire h (lanes h, 16+h, 32+h, 48+h)
        float fv = __shfl(act, h);
        float iv = __shfl(act, 16 + h);
        float gv = __shfl(act, 32 + h);
        float ov = __shfl(act, 48 + h);

        cx = fmaf(fv, cx, iv * gv);
        float e2 = __expf(2.0f * cx);
        float th = fmaf(-2.0f, __builtin_amdgcn_rcpf(1.0f + e2), 1.0f);
        hx = ov * th;

        if (lane < 10) outs[((size_t)t * 256 + b) * H_DIM + lane] = hx;
        zv = znext;
    }
}

// ---------------- kernel 3: hidden2tag + log_softmax, thread per row ----------------
__global__ __launch_bounds__(256) void k_head(const float* __restrict__ outs,
                                              const float* __restrict__ Wo,
                                              const float* __restrict__ bo,
                                              float* __restrict__ out) {
    const size_t row = blockIdx.x * 256 + threadIdx.x;   // < 65536
    float hx[10];
#pragma unroll
    for (int i = 0; i < 5; ++i) {
        float2 v = *(const float2*)&outs[row * H_DIM + 2 * i];
        hx[2 * i] = v.x; hx[2 * i + 1] = v.y;
    }
    float lg[50];
#pragma unroll
    for (int cI = 0; cI < 50; ++cI) {
        float l = bo[cI];
#pragma unroll
        for (int j = 0; j < 10; ++j) l = fmaf(hx[j], Wo[j * 50 + cI], l);
        lg[cI] = l;
    }
    float m = lg[0];
#pragma unroll
    for (int cI = 1; cI < 50; ++cI) m = fmaxf(m, lg[cI]);
    float sum = 0.0f;
#pragma unroll
    for (int cI = 0; cI < 50; ++cI) sum += __expf(lg[cI] - m);
    float lse = m + __logf(sum);
#pragma unroll
    for (int i = 0; i < 25; ++i) {
        float2 v = {lg[2 * i] - lse, lg[2 * i + 1] - lse};
        *(float2*)&out[row * 50 + 2 * i] = v;
    }
}

extern "C" void kernel_launch(void* const* d_in, const int* in_sizes, int n_in,
                              void* d_out, int out_size, void* d_ws, size_t ws_size,
                              hipStream_t stream) {
    const int*   sentence = (const int*)d_in[0];     // (256,256)
    const float* emb      = (const float*)d_in[1];   // (50257,1024)
    const float* Wg       = (const float*)d_in[2];   // (4,1034,10)
    const float* bg       = (const float*)d_in[3];   // (4,10)
    const float* theta    = (const float*)d_in[4];   // (4,10)
    const float* Wo       = (const float*)d_in[5];   // (10,50)
    const float* bo       = (const float*)d_in[6];   // (50,)
    float* out = (float*)d_out;

    float* ws = (float*)d_ws;
    unsigned short* Bfg = (unsigned short*)ws;            // 49152 shorts = 24576 floats
    float* zu   = ws + 24576;                             // 50257*40 floats (~8.0 MB)
    float* outs = zu + (size_t)V_DIM * NC;                // 65536*10

    k_wt<<<24, 256, 0, stream>>>(Wg, Bfg);
    k_gemm<<<786, 256, 0, stream>>>(emb, Bfg, zu);
    k_rnn<<<256, 128, 0, stream>>>(sentence, zu, Wg, bg, theta, outs);
    k_head<<<256, 256, 0, stream>>>(outs, Wo, bo, out);
}

// Round 5
// 384.444 us; speedup vs baseline: 1.0408x; 1.0069x over previous
//
#include <hip/hip_runtime.h>
#include <hip/hip_bf16.h>

// QLSTMClassifier: Embedding -> QLSTM (closed-form quantum layer) -> Linear -> log_softmax
// S=256 (batch==seq), E=1024, H=10, V=50257, T=50.
//
//  k_wt   : Wg x-part -> Bfg (bf16 MFMA B-fragments). unchanged.
//  k_gemm : DENSE STREAMING zu[v][40] = emb[v] @ W, ONE 16-row tile per
//           64-thread block (grid 3142). Removes the 786x4-wave block
//           imbalance tail (3.07 blocks/CU); tail quantum now ~64 KB.
//  k_rnn  : gather z-panel to LDS (one sync) -> wave0 serial chain (hx history
//           kept in LDS) -> second sync -> BOTH waves run the fused
//           hidden2tag + log_softmax head and write `out` directly.
//           Chain trims: 3 bpermutes (own act = f on row 0), exp2 folds.
//
// ws (floats): Bfg[24576 eq] | zu[50257*40]  (~8.1 MB)

#define E_DIM 1024
#define H_DIM 10
#define NC 40
#define V_DIM 50257
#define EHS 10340      // (E+H)*H per-gate Wg stride

typedef __attribute__((ext_vector_type(8))) short bf16x8;
typedef __attribute__((ext_vector_type(4))) float f32x4;

__device__ __forceinline__ unsigned short f2bf(float f) {
    unsigned u = __float_as_uint(f);
    unsigned r = u + 0x7FFFu + ((u >> 16) & 1u);   // RNE
    return (unsigned short)(r >> 16);
}

// ---------------- kernel 0: Wg -> bf16 B-fragments ----------------
// Bfg[((c*3+nt)*64+lane)*8 + j] = bf16(W[k][nc]), k=c*32+(lane>>4)*8+j, nc=nt*16+(lane&15)
__global__ __launch_bounds__(256) void k_wt(const float* __restrict__ Wg,
                                            unsigned short* __restrict__ Bfg) {
    int i = blockIdx.x * 256 + threadIdx.x;     // < 32*3*64 = 6144
    if (i >= 6144) return;
    int lane = i & 63, nt = (i >> 6) % 3, c = i / 192;
    int kg = lane >> 4, n = lane & 15;
    int nc = nt * 16 + n;
    unsigned short v[8];
#pragma unroll
    for (int j = 0; j < 8; ++j) {
        int k = c * 32 + kg * 8 + j;
        float w = 0.0f;
        if (nc < NC) {
            int g = nc / H_DIM, h = nc % H_DIM;
            w = Wg[g * EHS + k * H_DIM + h];
        }
        v[j] = f2bf(w);
    }
    bf16x8* dst = (bf16x8*)(Bfg + (size_t)i * 8);
    bf16x8 pk;
#pragma unroll
    for (int j = 0; j < 8; ++j) pk[j] = (short)v[j];
    *dst = pk;
}

// ---------------- kernel 1: DENSE vocab GEMM via MFMA ----------------
// One 16-row tile per 64-thread block; grid 3142 covers 50272 rows.
// ~12 blocks/CU -> balanced streaming, tiny tail quantum.
__global__ __launch_bounds__(64) void k_gemm(const float* __restrict__ emb,
                                             const unsigned short* __restrict__ Bfg,
                                             float* __restrict__ zu) {
    const int lane = threadIdx.x;
    const int R0 = blockIdx.x * 16;
    const int m = lane & 15, q = lane >> 4;

    int row = R0 + m;
    if (row > V_DIM - 1) row = V_DIM - 1;       // clamp loads; stores masked below
    const float* arow = emb + (size_t)row * E_DIM + q * 8;

    f32x4 acc0 = {0.f, 0.f, 0.f, 0.f}, acc1 = acc0, acc2 = acc0;

#pragma unroll 2
    for (int c = 0; c < 32; ++c) {
        f32x4 a0 = __builtin_nontemporal_load((const f32x4*)(arow + c * 32));
        f32x4 a1 = __builtin_nontemporal_load((const f32x4*)(arow + c * 32 + 4));
        bf16x8 b0 = *(const bf16x8*)(Bfg + ((size_t)(c * 3 + 0) * 64 + lane) * 8);
        bf16x8 b1 = *(const bf16x8*)(Bfg + ((size_t)(c * 3 + 1) * 64 + lane) * 8);
        bf16x8 b2 = *(const bf16x8*)(Bfg + ((size_t)(c * 3 + 2) * 64 + lane) * 8);
        bf16x8 af;
        af[0] = (short)f2bf(a0[0]); af[1] = (short)f2bf(a0[1]);
        af[2] = (short)f2bf(a0[2]); af[3] = (short)f2bf(a0[3]);
        af[4] = (short)f2bf(a1[0]); af[5] = (short)f2bf(a1[1]);
        af[6] = (short)f2bf(a1[2]); af[7] = (short)f2bf(a1[3]);
        acc0 = __builtin_amdgcn_mfma_f32_16x16x32_bf16(af, b0, acc0, 0, 0, 0);
        acc1 = __builtin_amdgcn_mfma_f32_16x16x32_bf16(af, b1, acc1, 0, 0, 0);
        acc2 = __builtin_amdgcn_mfma_f32_16x16x32_bf16(af, b2, acc2, 0, 0, 0);
    }

    // C/D layout: col = lane&15, row = (lane>>4)*4 + reg
    const int r0 = R0 + q * 4;
#pragma unroll
    for (int i = 0; i < 4; ++i) {
        int r = r0 + i;
        if (r < V_DIM) {
            size_t o = (size_t)r * NC;
            zu[o + m] = acc0[i];
            zu[o + 16 + m] = acc1[i];
            if (m < 8) zu[o + 32 + m] = acc2[i];
        }
    }
}

// ---------------- kernel 2: QLSTM recurrence + fused head ----------------
template <int CTRL>
__device__ __forceinline__ float dpp1(float x) {
    // shifted value; out-of-range lanes keep identity 1.0 (old value, bound_ctrl=false)
    return __int_as_float(__builtin_amdgcn_update_dpp(
        __float_as_int(1.0f), __float_as_int(x), CTRL, 0xF, 0xF, false));
}
#define ROW_SHR(n) (0x110 + (n))
#define ROW_SHL(n) (0x100 + (n))

__device__ __forceinline__ float rdlane(float v, int l) {
    return __int_as_float(__builtin_amdgcn_readlane(__float_as_int(v), l));
}

// block 128 (2 waves): all threads gather the z-panel into LDS (one sync);
// wave 0 runs the 256-step serial chain, storing hx history to LDS; second
// sync; both waves run the hidden2tag+log_softmax head for this b-column.
__global__ __launch_bounds__(128) void k_rnn(const int* __restrict__ idx,
                                             const float* __restrict__ zu,
                                             const float* __restrict__ Wg,
                                             const float* __restrict__ bg,
                                             const float* __restrict__ theta,
                                             const float* __restrict__ Wo,
                                             const float* __restrict__ bo,
                                             float* __restrict__ out) {
    __shared__ float zall[256 * NC];      // 40 KB: z for every step
    __shared__ float hist[256 * H_DIM];   // 10 KB: hx history
    const int tid = threadIdx.x;
    const int b = blockIdx.x;

    // ---- cooperative gather: thread covers rows (pass*32 + tid>>2), quarter tid&3 ----
    {
        const int j = tid >> 2;        // 0..31
        const int qq = tid & 3;        // quarter of the 40-float row
        int tok[8];
#pragma unroll
        for (int pass = 0; pass < 8; ++pass)
            tok[pass] = idx[(size_t)(pass * 32 + j) * 256 + b];
#pragma unroll
        for (int pass = 0; pass < 8; ++pass) {
            const float* src = zu + (size_t)tok[pass] * NC + qq * 10;
            float* dst = &zall[(pass * 32 + j) * NC + qq * 10];
#pragma unroll
            for (int e = 0; e < 5; ++e)
                *(float2*)(dst + 2 * e) = *(const float2*)(src + 2 * e);
        }
    }
    __syncthreads();

    if (tid < 64) {
        // ---- consumer wave: the serial chain ----
        const int lane = tid;
        const int r = lane >> 4;            // gate 0..3 (f,i,g,o)
        const int h = lane & 15;            // wire; valid < 10
        const int hc = (h < 10) ? h : 9;
        const int cidx = r * 10 + hc;

        float Wh[10];
#pragma unroll
        for (int j = 0; j < 10; ++j) Wh[j] = Wg[r * EHS + (E_DIM + j) * H_DIM + hc];
        const float bias = bg[cidx] + theta[cidx];

        // exp2-folded activation constants (tanh for r==2, sigmoid otherwise)
        const float kk2 = (r == 2) ? 2.8853900817779268f : -1.4426950408889634f;
        const float aa = (r == 2) ? 1.0f : 0.0f;
        const float bb = (r == 2) ? -2.0f : 1.0f;

        float cx = 0.0f, hx = 0.0f;
        float zv = zall[cidx];              // t = 0
#pragma unroll 8
        for (int t = 0; t < 256; ++t) {
            // prefetch next step's z early (hides ds_read latency under the chain)
            float znext = zall[((t < 255) ? (t + 1) : t) * NC + cidx];

            // hx[0..9] live on lanes 0..9 -> SGPR broadcasts
            float hv0 = rdlane(hx, 0), hv1 = rdlane(hx, 1), hv2 = rdlane(hx, 2),
                  hv3 = rdlane(hx, 3), hv4 = rdlane(hx, 4), hv5 = rdlane(hx, 5),
                  hv6 = rdlane(hx, 6), hv7 = rdlane(hx, 7), hv8 = rdlane(hx, 8),
                  hv9 = rdlane(hx, 9);
            float d0 = fmaf(hv0, Wh[0], fmaf(hv2, Wh[2],
                       fmaf(hv4, Wh[4], fmaf(hv6, Wh[6], hv8 * Wh[8]))));
            float d1 = fmaf(hv1, Wh[1], fmaf(hv3, Wh[3],
                       fmaf(hv5, Wh[5], fmaf(hv7, Wh[7], hv9 * Wh[9]))));
            float z = (zv + bias) + (d0 + d1);

            float cc = __builtin_amdgcn_cosf(z * 0.15915494309189535f);

            // inclusive prefix product P[h] = prod_{j<=h} c_j
            float pp = cc;
            pp *= dpp1<ROW_SHR(1)>(pp);
            pp *= dpp1<ROW_SHR(2)>(pp);
            pp *= dpp1<ROW_SHR(4)>(pp);
            pp *= dpp1<ROW_SHR(8)>(pp);
            // suffix product (pad lanes h>=10 with identity)
            float ss = (h < 10) ? cc : 1.0f;
            ss *= dpp1<ROW_SHL(1)>(ss);
            ss *= dpp1<ROW_SHL(2)>(ss);
            ss *= dpp1<ROW_SHL(4)>(ss);
            ss *= dpp1<ROW_SHL(8)>(ss);
            float tl = dpp1<ROW_SHL(1)>(ss);     // lane 0 -> prod_{j>=1}
            float qv = (h == 0) ? tl : pp;

            float e = __builtin_amdgcn_exp2f(kk2 * qv);
            float act = fmaf(bb, __builtin_amdgcn_rcpf(1.0f + e), aa);

            // gather i,g,o for wire h; own act IS f on row 0 (the only row consumed)
            float fv = act;
            float iv = __shfl(act, 16 + h);
            float gv = __shfl(act, 32 + h);
            float ov = __shfl(act, 48 + h);

            cx = fmaf(fv, cx, iv * gv);
            float e2 = __builtin_amdgcn_exp2f(2.8853900817779268f * cx);
            float th = fmaf(-2.0f, __builtin_amdgcn_rcpf(1.0f + e2), 1.0f);
            hx = ov * th;

            if (lane < 10) hist[t * H_DIM + lane] = hx;
            zv = znext;
        }
    }
    __syncthreads();

    // ---- fused head: 128 threads x 2 rows (t = tid, tid+128) ----
#pragma unroll
    for (int rr = 0; rr < 2; ++rr) {
        const int t = tid + rr * 128;
        float hv[10];
#pragma unroll
        for (int i = 0; i < 10; ++i) hv[i] = hist[t * H_DIM + i];
        float lg[50];
#pragma unroll
        for (int cI = 0; cI < 50; ++cI) {
            float l = bo[cI];
#pragma unroll
            for (int j = 0; j < 10; ++j) l = fmaf(hv[j], Wo[j * 50 + cI], l);
            lg[cI] = l;
        }
        float mx = lg[0];
#pragma unroll
        for (int cI = 1; cI < 50; ++cI) mx = fmaxf(mx, lg[cI]);
        float sum = 0.0f;
#pragma unroll
        for (int cI = 0; cI < 50; ++cI) sum += __expf(lg[cI] - mx);
        float lse = mx + __logf(sum);
        float* orow = out + ((size_t)t * 256 + b) * 50;
#pragma unroll
        for (int i = 0; i < 25; ++i) {
            float2 v = {lg[2 * i] - lse, lg[2 * i + 1] - lse};
            *(float2*)(orow + 2 * i) = v;
        }
    }
}

extern "C" void kernel_launch(void* const* d_in, const int* in_sizes, int n_in,
                              void* d_out, int out_size, void* d_ws, size_t ws_size,
                              hipStream_t stream) {
    const int*   sentence = (const int*)d_in[0];     // (256,256)
    const float* emb      = (const float*)d_in[1];   // (50257,1024)
    const float* Wg       = (const float*)d_in[2];   // (4,1034,10)
    const float* bg       = (const float*)d_in[3];   // (4,10)
    const float* theta    = (const float*)d_in[4];   // (4,10)
    const float* Wo       = (const float*)d_in[5];   // (10,50)
    const float* bo       = (const float*)d_in[6];   // (50,)
    float* out = (float*)d_out;

    float* ws = (float*)d_ws;
    unsigned short* Bfg = (unsigned short*)ws;            // 49152 shorts = 24576 floats
    float* zu   = ws + 24576;                             // 50257*40 floats (~8.0 MB)

    k_wt<<<24, 256, 0, stream>>>(Wg, Bfg);
    k_gemm<<<3142, 64, 0, stream>>>(emb, Bfg, zu);
    k_rnn<<<256, 128, 0, stream>>>(sentence, zu, Wg, bg, theta, Wo, bo, out);
}